// Round 3
// baseline (11949.765 us; speedup 1.0000x reference)
//
#include <hip/hip_runtime.h>
#include <math.h>

typedef _Float16 half_t;
typedef _Float16 half8 __attribute__((ext_vector_type(8)));
typedef float f32x4 __attribute__((ext_vector_type(4)));
typedef unsigned long long u64;

#define B_ 128
#define T_ 256
#define I_ 512
#define H_ 1024

// ---------------------------------------------------------------------------
// prep: convert x fp32 -> fp16 (8 elems/thread)
__global__ void k_convert_x(const float* __restrict__ x, half_t* __restrict__ x16, int n8) {
    int i = blockIdx.x * blockDim.x + threadIdx.x;
    if (i >= n8) return;
    const float4* xv = (const float4*)x;
    float4 a = xv[2 * i], b = xv[2 * i + 1];
    half8 o;
    o[0] = (half_t)a.x; o[1] = (half_t)a.y; o[2] = (half_t)a.z; o[3] = (half_t)a.w;
    o[4] = (half_t)b.x; o[5] = (half_t)b.y; o[6] = (half_t)b.z; o[7] = (half_t)b.w;
    ((half8*)x16)[i] = o;
}

// prep: pack W_ih|W_hh (fp32, torch gate order i,f,g,o) into fp16 MFMA
// B-fragment order. Layout: [hgroup(128)][kb(Ktot/32)][ntile(2)][lane(64)][j(8)]
__global__ void k_pack_w(const float* __restrict__ Wih, const float* __restrict__ Whh,
                         half_t* __restrict__ out, int Kx, int Ktot) {
    int idx = blockIdx.x * blockDim.x + threadIdx.x;
    int total = 4096 * Ktot;
    if (idx >= total) return;
    int j = idx & 7;
    int lane = (idx >> 3) & 63;
    int nt = (idx >> 9) & 1;
    int rest = idx >> 10;
    int nkb = Ktot >> 5;
    int kb = rest % nkb;
    int hg = rest / nkb;
    int nl = nt * 16 + (lane & 15);
    int gate = nl >> 3, hoff = nl & 7;
    int row = gate * 1024 + hg * 8 + hoff;
    int k = kb * 32 + (lane >> 4) * 8 + j;
    float v = (k < Kx) ? Wih[(size_t)row * Kx + k] : Whh[(size_t)row * 1024 + (k - Kx)];
    out[idx] = (half_t)v;
}

// prep: bias packed to [hgroup*32 + gate*8 + hoff], b_ih + b_hh summed
__global__ void k_pack_bias(const float* __restrict__ bih, const float* __restrict__ bhh,
                            float* __restrict__ out) {
    int idx = blockIdx.x * blockDim.x + threadIdx.x;
    if (idx >= 4096) return;
    int hg = idx >> 5, c = idx & 31;
    int gate = c >> 3, hoff = c & 7;
    int row = gate * 1024 + hg * 8 + hoff;
    out[idx] = bih[row] + bhh[row];
}

__global__ void k_zero(unsigned int* __restrict__ p, int n) {
    int i = blockIdx.x * blockDim.x + threadIdx.x;
    if (i < n) p[i] = 0u;
}

// ---------------------------------------------------------------------------
// system-scope (cache-bypassing, cross-XCD coherent) ops for reused h-state
__device__ __forceinline__ u64 sysld64(const half_t* p) {
    return __hip_atomic_load((const u64*)p, __ATOMIC_RELAXED, __HIP_MEMORY_SCOPE_SYSTEM);
}
__device__ __forceinline__ void sysst32(half_t* p, unsigned v) {
    __hip_atomic_store((unsigned*)p, v, __ATOMIC_RELAXED, __HIP_MEMORY_SCOPE_SYSTEM);
}
union H8U { half8 h; u64 u[2]; };

// 16 sub-counters (64B apart), 8 producers each. No cache-inv fences.
__device__ __forceinline__ void wait16(unsigned* base, unsigned tgt) {
    if (threadIdx.x < 64) {
        int l = threadIdx.x & 15;
        int gd = 0;
        while (__hip_atomic_load(base + l * 16, __ATOMIC_RELAXED,
                                 __HIP_MEMORY_SCOPE_SYSTEM) < tgt) {
            __builtin_amdgcn_s_sleep(2);
            if (++gd > (1 << 13)) break;  // failsafe: visible fail, not a hang
        }
    }
    __syncthreads();
}
__device__ __forceinline__ void signal16(unsigned* slot) {
    __syncthreads();  // drains vmcnt -> this block's stores globally visible
    if (threadIdx.x == 0)
        __hip_atomic_fetch_add(slot, 1u, __ATOMIC_RELEASE, __HIP_MEMORY_SCOPE_SYSTEM);
}

// ---------------------------------------------------------------------------
// Weights-in-VGPR persistent layer loop.
// Block = 512 thr = 8 waves = 8 K-slices (ks). Block tile: 64 rows x 32 cols
// (1 hgroup = cg). Wave: 4 rowtiles x 2 coltiles x K/8, B-frags in registers
// (loaded ONCE). LDS: gacc[8][64][32] f32 partials, 2-way-free swizzle.
// c-state lives in one register per thread. Per-step global traffic = A only.
template <int KX, bool LAY1>
__device__ void run_layer(const half_t* __restrict__ x16, half_t* __restrict__ h1seqT,
                          half_t* h2a, half_t* h2b,
                          const half_t* __restrict__ Wp, const float* __restrict__ biasp,
                          unsigned* ctrL0, unsigned* ctrOwn,
                          int rg, int cg, float* gacc)
{
    constexpr int KTOT = KX + 1024;
    constexpr int NKB  = KTOT >> 5;     // 48 / 64
    constexpr int NI   = NKB >> 3;      // 6 / 8 kbs per wave
    constexpr int NI_X = LAY1 ? 4 : 2;  // phase-1 kbs (kb < KX/32)

    const int tid = threadIdx.x;
    const int ks = tid >> 6, lane = tid & 63;
    const int q = lane >> 4, ml = lane & 15;
    const int hg = cg;
    const int sub = cg & 15;
    const int r0 = rg * 64;

    // ---- one-time B preload into registers (29.4MB total across the grid) ----
    half8 Breg[NI][2];
    {
        const half8* Wp8 = (const half8*)Wp;
        size_t base = (size_t)hg * NKB * 128 + lane;
#pragma unroll
        for (int i = 0; i < NI; ++i) {
#pragma unroll
            for (int nt = 0; nt < 2; ++nt)
                Breg[i][nt] = Wp8[base + (size_t)(ks + 8 * i) * 128 + nt * 64];
        }
    }
    // per-thread elementwise identity: (erow, ehoff)
    const int erow = tid >> 3, ehoff = tid & 7;
    const float bi = biasp[hg * 32 + 0 + ehoff];
    const float bf = biasp[hg * 32 + 8 + ehoff];
    const float bg = biasp[hg * 32 + 16 + ehoff];
    const float bo = biasp[hg * 32 + 24 + ehoff];
    float c_reg = 0.f;

    for (int t = 0; t < T_; ++t) {
        f32x4 acc[4][2];
#pragma unroll
        for (int rt = 0; rt < 4; ++rt) { acc[rt][0] = (f32x4)0.f; acc[rt][1] = (f32x4)0.f; }

        // ---- phase 1 ----
        if constexpr (LAY1) wait16(ctrL0, 8u * (unsigned)(t + 1));  // h1seq[t+1] ready
#pragma unroll
        for (int i = 0; i < NI_X; ++i) {
            int kg = (ks + 8 * i) * 32 + q * 8;
#pragma unroll
            for (int rt = 0; rt < 4; ++rt) {
                int grow = r0 + rt * 16 + ml;
                half8 a;
                if constexpr (!LAY1)
                    a = *(const half8*)(x16 + ((size_t)grow * T_ + t) * KX + kg);
                else
                    a = *(const half8*)(h1seqT + ((size_t)(t + 1) * B_ + grow) * H_ + kg);
                acc[rt][0] = __builtin_amdgcn_mfma_f32_16x16x32_f16(a, Breg[i][0], acc[rt][0], 0, 0, 0);
                acc[rt][1] = __builtin_amdgcn_mfma_f32_16x16x32_f16(a, Breg[i][1], acc[rt][1], 0, 0, 0);
            }
        }
        // ---- wait for own-layer recurrent state, then phase 2 ----
        if (t > 0) wait16(ctrOwn, 8u * (unsigned)t);
        const half_t* hsrc;
        if constexpr (!LAY1) hsrc = h1seqT + (size_t)t * B_ * H_;  // fresh lines: cached
        else hsrc = (t & 1) ? h2b : h2a;                           // reused: L2-bypass
#pragma unroll
        for (int i = NI_X; i < NI; ++i) {
            int kg = (ks + 8 * i) * 32 + q * 8 - KX;
#pragma unroll
            for (int rt = 0; rt < 4; ++rt) {
                int grow = r0 + rt * 16 + ml;
                half8 a;
                if constexpr (!LAY1) {
                    a = *(const half8*)(hsrc + (size_t)grow * H_ + kg);
                } else {
                    H8U u; const half_t* p = hsrc + (size_t)grow * H_ + kg;
                    u.u[0] = sysld64(p); u.u[1] = sysld64(p + 4);
                    a = u.h;
                }
                acc[rt][0] = __builtin_amdgcn_mfma_f32_16x16x32_f16(a, Breg[i][0], acc[rt][0], 0, 0, 0);
                acc[rt][1] = __builtin_amdgcn_mfma_f32_16x16x32_f16(a, Breg[i][1], acc[rt][1], 0, 0, 0);
            }
        }
        // ---- partials -> LDS (2-way-free swizzle) ----
#pragma unroll
        for (int rt = 0; rt < 4; ++rt)
#pragma unroll
            for (int ct = 0; ct < 2; ++ct)
#pragma unroll
                for (int r = 0; r < 4; ++r) {
                    int rl = rt * 16 + q * 4 + r;
                    int cl = ct * 16 + ml;
                    gacc[(ks * 64 + rl) * 32 + (cl ^ ((rl & 7) << 2))] = acc[rt][ct][r];
                }
        __syncthreads();
        // ---- reduce 8 partials + elementwise (all 512 threads, c in register) ----
        {
            int swz = (erow & 7) << 2;
            float pi = 0.f, pf = 0.f, pg = 0.f, po = 0.f;
#pragma unroll
            for (int z = 0; z < 8; ++z) {
                const float* g = &gacc[(z * 64 + erow) * 32];
                pi += g[(0 + ehoff) ^ swz];
                pf += g[(8 + ehoff) ^ swz];
                pg += g[(16 + ehoff) ^ swz];
                po += g[(24 + ehoff) ^ swz];
            }
            pi += bi; pf += bf; pg += bg; po += bo;
            float si = 1.f / (1.f + __expf(-pi));
            float sf = 1.f / (1.f + __expf(-pf));
            float so = 1.f / (1.f + __expf(-po));
            float tg = 1.f - 2.f / (__expf(2.f * pg) + 1.f);
            c_reg = sf * c_reg + si * tg;
            float th = 1.f - 2.f / (__expf(2.f * c_reg) + 1.f);
            float hn = so * th;
            union { _Float16 hf; unsigned short us; } cvt; cvt.hf = (_Float16)hn;
            unsigned mine = cvt.us;
            unsigned other = (unsigned)__shfl_down((int)mine, 1, 64);
            if ((ehoff & 1) == 0) {
                unsigned pk = mine | ((other & 0xffffu) << 16);
                int grow = r0 + erow;
                half_t* dst;
                if constexpr (!LAY1)
                    dst = h1seqT + ((size_t)(t + 1) * B_ + grow) * H_ + hg * 8 + ehoff;
                else
                    dst = ((t & 1) ? h2a : h2b) + (size_t)grow * H_ + hg * 8 + ehoff;
                sysst32(dst, pk);
            }
        }
        signal16(ctrOwn + sub * 16);
    }
}

// ---------------------------------------------------------------------------
// 512 blocks, all resident (2/CU: VGPR<=128 via launch_bounds, LDS 64KB).
// bid&1 = layer, (bid>>1)&1 = rg, bid>>2 = cg. Co-CU pair (b, b+256) shares
// layer+rg -> A-fragment reads overlap in L1/L2.
__launch_bounds__(512, 4)
__global__ void lstm_persist(const half_t* __restrict__ x16, half_t* h1seqT,
                             const half_t* __restrict__ wp0, const half_t* __restrict__ wp1,
                             const float* __restrict__ bias0, const float* __restrict__ bias1,
                             half_t* h2a, half_t* h2b,
                             unsigned* __restrict__ ctrs)
{
    __shared__ float gacc[8 * 64 * 32];  // 64 KB
    int bid = blockIdx.x;
    int lay = bid & 1;
    int rg = (bid >> 1) & 1;
    int cg = bid >> 2;
    unsigned* ctrL0  = ctrs + (0 * 2 + rg) * 256;  // 16 slots x 16 u32 per group
    unsigned* ctrL1  = ctrs + (1 * 2 + rg) * 256;
    int sub = cg & 15;

    if (lay == 0)
        run_layer<512, false>(x16, h1seqT, h2a, h2b, wp0, bias0,
                              ctrL0, ctrL0, rg, cg, gacc);
    else
        run_layer<1024, true>(x16, h1seqT, h2a, h2b, wp1, bias1,
                              ctrL0, ctrL1, rg, cg, gacc);
    (void)sub;
}

// final FC: out[m] = sum_k h[m][k] * Wfc[k] + bfc  (NC=1)
__global__ void k_fc(const half_t* __restrict__ h, const float* __restrict__ Wfc,
                     const float* __restrict__ bfc, float* __restrict__ out) {
    int m = blockIdx.x, lane = threadIdx.x;
    float s = 0.f;
    for (int k = lane; k < H_; k += 64) s += (float)h[m * H_ + k] * Wfc[k];
#pragma unroll
    for (int o = 32; o; o >>= 1) s += __shfl_down(s, o, 64);
    if (lane == 0) out[m] = s + bfc[0];
}

// ---------------------------------------------------------------------------
extern "C" void kernel_launch(void* const* d_in, const int* in_sizes, int n_in,
                              void* d_out, int out_size, void* d_ws, size_t ws_size,
                              hipStream_t stream) {
    const float* x    = (const float*)d_in[0];
    const float* Wih0 = (const float*)d_in[1];
    const float* Whh0 = (const float*)d_in[2];
    const float* bih0 = (const float*)d_in[3];
    const float* bhh0 = (const float*)d_in[4];
    const float* Wih1 = (const float*)d_in[5];
    const float* Whh1 = (const float*)d_in[6];
    const float* bih1 = (const float*)d_in[7];
    const float* bhh1 = (const float*)d_in[8];
    const float* Wfc  = (const float*)d_in[9];
    const float* bfc  = (const float*)d_in[10];
    float* out = (float*)d_out;

    char* ws = (char*)d_ws;
    size_t off = 0;
    auto carve = [&](size_t bytes) { void* p = ws + off; off += (bytes + 255) & ~(size_t)255; return p; };
    half_t* x16    = (half_t*)carve((size_t)B_ * T_ * I_ * 2);              // 33.5 MB
    half_t* h1seqT = (half_t*)carve((size_t)(T_ + 1) * B_ * H_ * 2);        // 67.4 MB [t][row][unit]
    half_t* wp0    = (half_t*)carve((size_t)4096 * 1536 * 2);               // 12.6 MB
    half_t* wp1    = (half_t*)carve((size_t)4096 * 2048 * 2);               // 16.8 MB
    float*  bias0  = (float*)carve(4096 * 4);
    float*  bias1  = (float*)carve(4096 * 4);
    // states: h2a,h2b (fp16) + counters (4 KB). c-state now lives in registers.
    char*   states = (char*)carve(2 * (size_t)B_ * H_ * 2 + 4096);
    if (off > ws_size) return;  // ws too small: visible failure

    half_t* h2a = (half_t*)states;
    half_t* h2b = h2a + B_ * H_;
    unsigned* ctrs = (unsigned*)(h2b + B_ * H_);

    // prep
    k_convert_x<<<(B_ * T_ * I_ / 8 + 255) / 256, 256, 0, stream>>>(x, x16, B_ * T_ * I_ / 8);
    k_pack_w<<<(4096 * 1536 + 255) / 256, 256, 0, stream>>>(Wih0, Whh0, wp0, 512, 1536);
    k_pack_w<<<(4096 * 2048 + 255) / 256, 256, 0, stream>>>(Wih1, Whh1, wp1, 1024, 2048);
    k_pack_bias<<<16, 256, 0, stream>>>(bih0, bhh0, bias0);
    k_pack_bias<<<16, 256, 0, stream>>>(bih1, bhh1, bias1);
    // zero h1seqT slot 0 (initial h for layer 0) — every launch (bench replays)
    k_zero<<<(B_ * H_ / 2 + 255) / 256, 256, 0, stream>>>((unsigned int*)h1seqT, B_ * H_ / 2);
    // zero h2a,h2b,counters — every launch
    {
        int n = (2 * B_ * H_ * 2 + 4096) / 4;
        k_zero<<<(n + 255) / 256, 256, 0, stream>>>((unsigned int*)states, n);
    }

    // persistent, weights-in-registers, pipelined layers
    lstm_persist<<<dim3(512), dim3(512), 0, stream>>>(
        x16, h1seqT, wp0, wp1, bias0, bias1, h2a, h2b, ctrs);

    // final h2 state after t=255 (odd) lives in h2a
    k_fc<<<128, 64, 0, stream>>>(h2a, Wfc, bfc, out);
}

// Round 4
// 6907.806 us; speedup vs baseline: 1.7299x; 1.7299x over previous
//
#include <hip/hip_runtime.h>
#include <math.h>

typedef _Float16 half_t;
typedef _Float16 half8 __attribute__((ext_vector_type(8)));
typedef float f32x4 __attribute__((ext_vector_type(4)));
typedef unsigned long long u64;

#define B_ 128
#define T_ 256
#define I_ 512
#define H_ 1024

#define mfma16 __builtin_amdgcn_mfma_f32_16x16x32_f16

// ---------------------------------------------------------------------------
// prep: convert x fp32 -> fp16, TRANSPOSED to [t][row][k] (per-step slab = 128KB)
__global__ void k_convert_x(const float* __restrict__ x, half_t* __restrict__ x16, int n8) {
    int i = blockIdx.x * blockDim.x + threadIdx.x;
    if (i >= n8) return;
    const float4* xv = (const float4*)x;
    float4 a = xv[2 * i], b = xv[2 * i + 1];
    half8 o;
    o[0] = (half_t)a.x; o[1] = (half_t)a.y; o[2] = (half_t)a.z; o[3] = (half_t)a.w;
    o[4] = (half_t)b.x; o[5] = (half_t)b.y; o[6] = (half_t)b.z; o[7] = (half_t)b.w;
    int e = i * 8;
    int k = e & (I_ - 1);
    int t = (e >> 9) & (T_ - 1);
    int row = e >> 17;
    ((half8*)x16)[(((size_t)t * B_ + row) * I_ + k) >> 3] = o;
}

// prep: pack W_ih|W_hh (fp32, torch gate order i,f,g,o) into fp16 MFMA
// B-fragment order. Layout: [hgroup(128)][kb(Ktot/32)][ntile(2)][lane(64)][j(8)]
__global__ void k_pack_w(const float* __restrict__ Wih, const float* __restrict__ Whh,
                         half_t* __restrict__ out, int Kx, int Ktot) {
    int idx = blockIdx.x * blockDim.x + threadIdx.x;
    int total = 4096 * Ktot;
    if (idx >= total) return;
    int j = idx & 7;
    int lane = (idx >> 3) & 63;
    int nt = (idx >> 9) & 1;
    int rest = idx >> 10;
    int nkb = Ktot >> 5;
    int kb = rest % nkb;
    int hg = rest / nkb;
    int nl = nt * 16 + (lane & 15);
    int gate = nl >> 3, hoff = nl & 7;
    int row = gate * 1024 + hg * 8 + hoff;
    int k = kb * 32 + (lane >> 4) * 8 + j;
    float v = (k < Kx) ? Wih[(size_t)row * Kx + k] : Whh[(size_t)row * 1024 + (k - Kx)];
    out[idx] = (half_t)v;
}

// prep: bias packed to [hgroup*32 + gate*8 + hoff], b_ih + b_hh summed
__global__ void k_pack_bias(const float* __restrict__ bih, const float* __restrict__ bhh,
                            float* __restrict__ out) {
    int idx = blockIdx.x * blockDim.x + threadIdx.x;
    if (idx >= 4096) return;
    int hg = idx >> 5, c = idx & 31;
    int gate = c >> 3, hoff = c & 7;
    int row = gate * 1024 + hg * 8 + hoff;
    out[idx] = bih[row] + bhh[row];
}

__global__ void k_zero(unsigned int* __restrict__ p, int n) {
    int i = blockIdx.x * blockDim.x + threadIdx.x;
    if (i < n) p[i] = 0u;
}

// ---------------------------------------------------------------------------
// system-scope primitives (validated rounds 2/3: write-through store + fresh
// cached read is coherent; sysld for reused addresses)
__device__ __forceinline__ u64 sysld64(const half_t* p) {
    return __hip_atomic_load((const u64*)p, __ATOMIC_RELAXED, __HIP_MEMORY_SCOPE_SYSTEM);
}
__device__ __forceinline__ void sysst32(half_t* p, unsigned v) {
    __hip_atomic_store((unsigned*)p, v, __ATOMIC_RELAXED, __HIP_MEMORY_SCOPE_SYSTEM);
}
union H8U { half8 h; u64 u[2]; };

// 16 sub-counter slots (64B apart), 8 producers each. No cache-inv fences.
__device__ __forceinline__ void wait16(unsigned* base, unsigned tgt) {
    if (threadIdx.x < 64) {
        int l = threadIdx.x & 15;
        int gd = 0;
        while (__hip_atomic_load(base + l * 16, __ATOMIC_RELAXED,
                                 __HIP_MEMORY_SCOPE_SYSTEM) < tgt) {
            __builtin_amdgcn_s_sleep(2);
            if (++gd > (1 << 14)) break;  // failsafe: visible fail, not a hang
        }
    }
    __syncthreads();
}
__device__ __forceinline__ void signal16(unsigned* slot) {
    __syncthreads();  // drains vmcnt -> this block's stores globally visible
    if (threadIdx.x == 0)
        __hip_atomic_fetch_add(slot, 1u, __ATOMIC_RELEASE, __HIP_MEMORY_SCOPE_SYSTEM);
}

// ---------------------------------------------------------------------------
// One layer, persistent. Block = 512 thr = 8 waves = 8 K-slices.
// Block tile: 32 rows (rg) x 32 gate-cols (cg == hgroup). Weights in VGPRs,
// PINNED via opaque asm so the compiler cannot rematerialize the loads.
// LDS gacc[8][32][32] f32 partials. c-state in one register (tid<256).
// srcX: phase-1 operand, time-indexed [t1][B][KX] (x16T for L0, h1seq for L1).
// hA/hB: recurrent state. H2SEQ: time-indexed hA[t][B][H] (cached reads);
// else ping-pong hA/hB with system-scope (L2-bypass) reads.
template <int KX, bool LAY1, bool H2SEQ>
__device__ void run_layer(const half_t* __restrict__ srcX,
                          half_t* hA, half_t* hB,
                          const half_t* __restrict__ Wp, const float* __restrict__ biasp,
                          unsigned* ctrPre, unsigned* ctrOwn,
                          int rg, int cg, float* gacc)
{
    constexpr int KTOT = KX + 1024;
    constexpr int NKB  = KTOT >> 5;   // 48 / 64
    constexpr int NI   = NKB >> 3;    // 6 / 8 kbs per wave
    constexpr int NI_X = KX >> 8;     // 2 / 4 phase-1 kbs

    const int tid = threadIdx.x;
    const int ks = tid >> 6, lane = tid & 63;
    const int q = lane >> 4, ml = lane & 15;
    const int hg = cg;
    const int r0 = rg * 32;

    // ---- one-time weight preload into VGPRs, pinned ----
    half8 Breg[NI][2];
    {
        const half8* Wp8 = (const half8*)Wp;
        size_t base = (size_t)hg * NKB * 128 + lane;
#pragma unroll
        for (int i = 0; i < NI; ++i) {
            Breg[i][0] = Wp8[base + (size_t)(ks + 8 * i) * 128];
            Breg[i][1] = Wp8[base + (size_t)(ks + 8 * i) * 128 + 64];
        }
#pragma unroll
        for (int i = 0; i < NI; ++i)
            asm volatile("" : "+v"(Breg[i][0]), "+v"(Breg[i][1]));  // no remat/sink
    }

    const int erow = tid >> 3, ehoff = tid & 7;  // elementwise id (tid<256)
    float bi = 0.f, bf = 0.f, bgc = 0.f, bo = 0.f;
    if (tid < 256) {
        bi  = biasp[hg * 32 + 0 + ehoff];
        bf  = biasp[hg * 32 + 8 + ehoff];
        bgc = biasp[hg * 32 + 16 + ehoff];
        bo  = biasp[hg * 32 + 24 + ehoff];
    }
    float c_reg = 0.f;

    for (int t = 0; t < T_; ++t) {
        f32x4 acc[2][2];
        acc[0][0] = (f32x4)0.f; acc[0][1] = (f32x4)0.f;
        acc[1][0] = (f32x4)0.f; acc[1][1] = (f32x4)0.f;

        // phase 1: non-recurrent operand (x for L0, h1seq[t+1] for L1)
        if constexpr (LAY1) wait16(ctrPre, 8u * (unsigned)(t + 1));  // instant for t<255
        const int t1 = LAY1 ? (t + 1) : t;
#pragma unroll
        for (int i = 0; i < NI_X; ++i) {
            int kg = (ks + 8 * i) * 32 + q * 8;
#pragma unroll
            for (int rt = 0; rt < 2; ++rt) {
                int grow = r0 + rt * 16 + ml;
                half8 a = *(const half8*)(srcX + ((size_t)t1 * B_ + grow) * KX + kg);
                acc[rt][0] = mfma16(a, Breg[i][0], acc[rt][0], 0, 0, 0);
                acc[rt][1] = mfma16(a, Breg[i][1], acc[rt][1], 0, 0, 0);
            }
        }
        // phase 2: recurrent operand
        if (t > 0) wait16(ctrOwn, 8u * (unsigned)t);
        const half_t* hp;
        if constexpr (!LAY1 || H2SEQ) hp = hA + (size_t)t * B_ * H_;
        else                          hp = (t & 1) ? hB : hA;
#pragma unroll
        for (int i = NI_X; i < NI; ++i) {
            int kg2 = (ks + 8 * i) * 32 + q * 8 - KX;
#pragma unroll
            for (int rt = 0; rt < 2; ++rt) {
                int grow = r0 + rt * 16 + ml;
                half8 a;
                if constexpr (LAY1 && !H2SEQ) {
                    H8U u; const half_t* p = hp + (size_t)grow * H_ + kg2;
                    u.u[0] = sysld64(p); u.u[1] = sysld64(p + 4);
                    a = u.h;
                } else {
                    a = *(const half8*)(hp + (size_t)grow * H_ + kg2);
                }
                acc[rt][0] = mfma16(a, Breg[i][0], acc[rt][0], 0, 0, 0);
                acc[rt][1] = mfma16(a, Breg[i][1], acc[rt][1], 0, 0, 0);
            }
        }
        // partials -> LDS (<=2-way conflicts)
#pragma unroll
        for (int rt = 0; rt < 2; ++rt)
#pragma unroll
            for (int ct = 0; ct < 2; ++ct)
#pragma unroll
                for (int r = 0; r < 4; ++r) {
                    int rl = rt * 16 + q * 4 + r;
                    int cl = ct * 16 + ml;
                    gacc[(ks * 32 + rl) * 32 + (cl ^ ((rl & 7) << 2))] = acc[rt][ct][r];
                }
        __syncthreads();
        // reduce 8 K-slices + elementwise (tid<256), c in register
        if (tid < 256) {
            int swz = (erow & 7) << 2;
            float pi = 0.f, pf = 0.f, pg = 0.f, po = 0.f;
#pragma unroll
            for (int z = 0; z < 8; ++z) {
                const float* g = &gacc[(z * 32 + erow) * 32];
                pi += g[(0 + ehoff) ^ swz];
                pf += g[(8 + ehoff) ^ swz];
                pg += g[(16 + ehoff) ^ swz];
                po += g[(24 + ehoff) ^ swz];
            }
            pi += bi; pf += bf; pg += bgc; po += bo;
            float si = 1.f / (1.f + __expf(-pi));
            float sf = 1.f / (1.f + __expf(-pf));
            float so = 1.f / (1.f + __expf(-po));
            float tg = 1.f - 2.f / (__expf(2.f * pg) + 1.f);
            c_reg = sf * c_reg + si * tg;
            float th = 1.f - 2.f / (__expf(2.f * c_reg) + 1.f);
            float hn = so * th;
            union { _Float16 hf; unsigned short us; } cvt; cvt.hf = (_Float16)hn;
            unsigned mine = cvt.us;
            unsigned other = (unsigned)__shfl_down((int)mine, 1, 64);
            if ((ehoff & 1) == 0) {  // pack pair -> one u32 write-through store
                unsigned pk = mine | ((other & 0xffffu) << 16);
                int grow = r0 + erow;
                half_t* dst;
                if constexpr (!LAY1 || H2SEQ)
                    dst = hA + ((size_t)(t + 1) * B_ + grow) * H_ + hg * 8 + ehoff;
                else
                    dst = ((t & 1) ? hA : hB) + (size_t)grow * H_ + hg * 8 + ehoff;
                sysst32(dst, pk);
            }
        }
        signal16(ctrOwn + (cg & 15) * 16);
    }
}

// ---------------------------------------------------------------------------
// 512 blocks x 512 thr, 2 blocks/CU (VGPR cap 128, LDS 32KB). Sequential
// layers. bid decode keeps each rg-group on exactly 2 XCDs (bid&7 fixes rg).
template <bool H2SEQ>
__launch_bounds__(512, 4)
__global__ void lstm_persist(const half_t* __restrict__ x16T, half_t* h1seq,
                             half_t* h2A, half_t* h2B,
                             const half_t* __restrict__ wp0, const half_t* __restrict__ wp1,
                             const float* __restrict__ bias0, const float* __restrict__ bias1,
                             unsigned* __restrict__ ctrs)
{
    __shared__ float gacc[8 * 32 * 32];  // 32 KB
    int bid = blockIdx.x;
    int rg = (bid >> 1) & 3;
    int cg = ((bid >> 3) << 1) | (bid & 1);
    unsigned* ctrL0 = ctrs + rg * 256;          // [rg][16 slots][16 u32]
    unsigned* ctrL1 = ctrs + 1024 + rg * 256;

    run_layer<512, false, true>(x16T, h1seq, (half_t*)0, wp0, bias0,
                                ctrL0, ctrL0, rg, cg, gacc);
    run_layer<1024, true, H2SEQ>(h1seq, h2A, h2B, wp1, bias1,
                                 ctrL0, ctrL1, rg, cg, gacc);
}

// final FC: out[m] = sum_k h[m][k] * Wfc[k] + bfc  (NC=1)
__global__ void k_fc(const half_t* __restrict__ h, const float* __restrict__ Wfc,
                     const float* __restrict__ bfc, float* __restrict__ out) {
    int m = blockIdx.x, lane = threadIdx.x;
    float s = 0.f;
    for (int k = lane; k < H_; k += 64) s += (float)h[m * H_ + k] * Wfc[k];
#pragma unroll
    for (int o = 32; o; o >>= 1) s += __shfl_down(s, o, 64);
    if (lane == 0) out[m] = s + bfc[0];
}

// ---------------------------------------------------------------------------
extern "C" void kernel_launch(void* const* d_in, const int* in_sizes, int n_in,
                              void* d_out, int out_size, void* d_ws, size_t ws_size,
                              hipStream_t stream) {
    const float* x    = (const float*)d_in[0];
    const float* Wih0 = (const float*)d_in[1];
    const float* Whh0 = (const float*)d_in[2];
    const float* bih0 = (const float*)d_in[3];
    const float* bhh0 = (const float*)d_in[4];
    const float* Wih1 = (const float*)d_in[5];
    const float* Whh1 = (const float*)d_in[6];
    const float* bih1 = (const float*)d_in[7];
    const float* bhh1 = (const float*)d_in[8];
    const float* Wfc  = (const float*)d_in[9];
    const float* bfc  = (const float*)d_in[10];
    float* out = (float*)d_out;

    char* ws = (char*)d_ws;
    size_t off = 0;
    auto carve = [&](size_t bytes) { void* p = ws + off; off += (bytes + 255) & ~(size_t)255; return p; };
    half_t* x16T   = (half_t*)carve((size_t)B_ * T_ * I_ * 2);              // 33.5 MB [t][B][512]
    half_t* h1seq  = (half_t*)carve((size_t)(T_ + 1) * B_ * H_ * 2);        // 67.4 MB [t][B][H]
    half_t* wp0    = (half_t*)carve((size_t)4096 * 1536 * 2);               // 12.6 MB
    half_t* wp1    = (half_t*)carve((size_t)4096 * 2048 * 2);               // 16.8 MB
    float*  bias0  = (float*)carve(4096 * 4);
    float*  bias1  = (float*)carve(4096 * 4);
    char*   states = (char*)carve(2 * (size_t)B_ * H_ * 2 + 8192);          // h2a,h2b,ctrs
    if (off > ws_size) return;  // base footprint ~131 MB: visible failure if too small

    half_t* h2a = (half_t*)states;
    half_t* h2b = h2a + B_ * H_;
    unsigned* ctrs = (unsigned*)(h2b + B_ * H_);

    // optional fast path: time-indexed h2seq (cached reads) if workspace allows
    half_t* h2seq = nullptr;
    if (off + (size_t)(T_ + 1) * B_ * H_ * 2 + 256 <= ws_size)
        h2seq = (half_t*)carve((size_t)(T_ + 1) * B_ * H_ * 2);             // +67.4 MB

    // prep
    k_convert_x<<<(B_ * T_ * I_ / 8 + 255) / 256, 256, 0, stream>>>(x, x16T, B_ * T_ * I_ / 8);
    k_pack_w<<<(4096 * 1536 + 255) / 256, 256, 0, stream>>>(Wih0, Whh0, wp0, 512, 1536);
    k_pack_w<<<(4096 * 2048 + 255) / 256, 256, 0, stream>>>(Wih1, Whh1, wp1, 1024, 2048);
    k_pack_bias<<<16, 256, 0, stream>>>(bih0, bhh0, bias0);
    k_pack_bias<<<16, 256, 0, stream>>>(bih1, bhh1, bias1);
    // per-launch zeroing (bench replays): h1seq[0], states(+ctrs), h2seq[0]
    k_zero<<<(B_ * H_ / 2 + 255) / 256, 256, 0, stream>>>((unsigned int*)h1seq, B_ * H_ / 2);
    {
        int n = (2 * B_ * H_ * 2 + 8192) / 4;
        k_zero<<<(n + 255) / 256, 256, 0, stream>>>((unsigned int*)states, n);
    }
    if (h2seq)
        k_zero<<<(B_ * H_ / 2 + 255) / 256, 256, 0, stream>>>((unsigned int*)h2seq, B_ * H_ / 2);

    // persistent, sequential layers, weights pinned in VGPRs
    if (h2seq) {
        lstm_persist<true><<<dim3(512), dim3(512), 0, stream>>>(
            x16T, h1seq, h2seq, (half_t*)0, wp0, wp1, bias0, bias1, ctrs);
        k_fc<<<128, 64, 0, stream>>>(h2seq + (size_t)T_ * B_ * H_, Wfc, bfc, out);
    } else {
        lstm_persist<false><<<dim3(512), dim3(512), 0, stream>>>(
            x16T, h1seq, h2a, h2b, wp0, wp1, bias0, bias1, ctrs);
        // t=255 (odd) writes h2a
        k_fc<<<128, 64, 0, stream>>>(h2a, Wfc, bfc, out);
    }
}